// Round 14
// baseline (144.948 us; speedup 1.0000x reference)
//
#include <hip/hip_runtime.h>

#define T_DIM 8192
#define D_DIM 256
#define N_DIM 64
#define LOG2E 1.44269504f

typedef __bf16 bf16x8 __attribute__((ext_vector_type(8)));
typedef __bf16 bf16x4 __attribute__((ext_vector_type(4)));
typedef float f32x16 __attribute__((ext_vector_type(16)));

__device__ __forceinline__ f32x16 zero16() {
  f32x16 v;
#pragma unroll
  for (int i = 0; i < 16; ++i) v[i] = 0.f;
  return v;
}

// DHf: fragment-major. Row-group G=t>>5, chunk c=kk*2+h, lane l31:
// DHf[G*2048 + c*256 + l31*8 .. +7] = DH[n=c*8+e][t=G*32+l31].

// ---------------------------------------------------------------------------
// K1 v2: DHf + lbe + rowsum=0. t32 blocks, grid 256 x 256 — full machine,
//     4 waves = nh(2 n-tiles) x kh(2 K-halves), K-split partials reduced in
//     LDS. 47KB LDS -> 3 blk/CU.  (R12-proven)
// ---------------------------------------------------------------------------
__global__ __launch_bounds__(256) void k_dh(const float* __restrict__ H,
                                            const float* __restrict__ Dm,
                                            __bf16* __restrict__ DHf,
                                            float* __restrict__ lbe,
                                            float* __restrict__ rowsum) {
  __shared__ __bf16 HlThi[32 * 264];
  __shared__ __bf16 HlTlo[32 * 264];
  __shared__ __bf16 DHs[32 * 72];
  __shared__ float redf[2][32][33];
  const int tid = threadIdx.x;
  const int t0 = blockIdx.x * 32;
  const int lane = tid & 63;
  const int wave = tid >> 6;  // 0..3
  const int h = lane >> 5;
  const int l31 = lane & 31;
  const float4* H4 = (const float4*)H;
#pragma unroll
  for (int r = 0; r < 8; ++r) {
    int idx = r * 256 + tid;
    int d = idx >> 3, tc = idx & 7;
    float4 v = H4[(size_t)d * (T_DIM / 4) + (t0 >> 2) + tc];
    float vv[4] = {v.x, v.y, v.z, v.w};
#pragma unroll
    for (int i = 0; i < 4; ++i) {
      __bf16 hi = (__bf16)vv[i];
      float lo = vv[i] - (float)hi;
      HlThi[(tc * 4 + i) * 264 + d] = hi;
      HlTlo[(tc * 4 + i) * 264 + d] = (__bf16)lo;
    }
  }
  __syncthreads();
  const int nh = wave & 1;   // n-tile
  const int kh = wave >> 1;  // K-half
  const int m = l31;
  const int n = nh * 32 + l31;
  f32x16 c = zero16();
#pragma unroll
  for (int kq = 0; kq < 8; ++kq) {
    const int kk = kh * 8 + kq;
    bf16x8 ahi = *(const bf16x8*)&HlThi[m * 264 + kk * 16 + h * 8];
    bf16x8 alo = *(const bf16x8*)&HlTlo[m * 264 + kk * 16 + h * 8];
    const float4* dp = (const float4*)(Dm + (size_t)n * 256 + kk * 16 + h * 8);
    float4 b0 = dp[0], b1 = dp[1];
    float bv[8] = {b0.x, b0.y, b0.z, b0.w, b1.x, b1.y, b1.z, b1.w};
    bf16x8 bhi, blo;
#pragma unroll
    for (int i = 0; i < 8; ++i) {
      __bf16 hi = (__bf16)bv[i];
      bhi[i] = hi;
      blo[i] = (__bf16)(bv[i] - (float)hi);
    }
    c = __builtin_amdgcn_mfma_f32_32x32x16_bf16(ahi, bhi, c, 0, 0, 0);
    c = __builtin_amdgcn_mfma_f32_32x32x16_bf16(ahi, blo, c, 0, 0, 0);
    c = __builtin_amdgcn_mfma_f32_32x32x16_bf16(alo, bhi, c, 0, 0, 0);
  }
  if (kh == 1) {
#pragma unroll
    for (int r = 0; r < 16; ++r) {
      int row = (r & 3) + 8 * (r >> 2) + 4 * h;
      redf[nh][row][l31] = c[r];
    }
  }
  __syncthreads();
  if (kh == 0) {
#pragma unroll
    for (int r = 0; r < 16; ++r) {
      int row = (r & 3) + 8 * (r >> 2) + 4 * h;
      DHs[row * 72 + n] = (__bf16)(c[r] + redf[nh][row][l31]);
    }
  }
  __syncthreads();
  {  // export: 256 threads cover cc(8) x l(32)
    int cc = tid >> 5, l = tid & 31;
    bf16x8 w = *(const bf16x8*)&DHs[l * 72 + cc * 8];
    *(bf16x8*)(DHf + (size_t)blockIdx.x * 2048 + cc * 256 + l * 8) = w;
  }
  if (tid < 32) {
    float s = 0.f;
#pragma unroll
    for (int q = 0; q < 8; ++q) {
      bf16x8 w = *(const bf16x8*)&DHs[tid * 72 + q * 8];
#pragma unroll
      for (int i = 0; i < 8; ++i) { float f = (float)w[i]; s += f * f; }
    }
    lbe[t0 + tid] = -0.5f * s * LOG2E;
    rowsum[t0 + tid] = 0.f;
  }
}

// ---------------------------------------------------------------------------
// K2 v4: rowsum[t] += sum_j exp(S+lb). grid 512 x 512.  (R10-proven)
// ---------------------------------------------------------------------------
__global__ __launch_bounds__(512, 4) void k_rowsum(const __bf16* __restrict__ DHf,
                                                   const float* __restrict__ lbe,
                                                   float* __restrict__ rowsum) {
  __shared__ float red2[256][33];
  const int tid = threadIdx.x;
  const int lane = tid & 63;
  const int wave = tid >> 6;
  const int h = lane >> 5;
  const int l31 = lane & 31;
  const int t0 = (int)(blockIdx.x >> 4) * 256;
  const int jbase = (int)(blockIdx.x & 15) * 512;
  const size_t Gt = (size_t)(t0 >> 5) + wave;
  const size_t Gj0 = (size_t)(jbase >> 5);
  bf16x8 aR[4];
#pragma unroll
  for (int kk = 0; kk < 4; ++kk)
    aR[kk] = *(const bf16x8*)(DHf + Gt * 2048 + kk * 512 + lane * 8);
  float racc[16];
#pragma unroll
  for (int r = 0; r < 16; ++r) racc[r] = 0.f;
  bf16x8 b0[4], b1[4];
#pragma unroll
  for (int kk = 0; kk < 4; ++kk) {
    b0[kk] = *(const bf16x8*)(DHf + Gj0 * 2048 + kk * 512 + lane * 8);
    b1[kk] = *(const bf16x8*)(DHf + (Gj0 + 1) * 2048 + kk * 512 + lane * 8);
  }
#pragma unroll
  for (int jj = 0; jj < 8; ++jj) {
    {
      const float lbv = lbe[jbase + (jj * 2) * 32 + l31];
      f32x16 s0 = zero16(), s1 = zero16();
      s0 = __builtin_amdgcn_mfma_f32_32x32x16_bf16(aR[0], b0[0], s0, 0, 0, 0);
      s1 = __builtin_amdgcn_mfma_f32_32x32x16_bf16(aR[1], b0[1], s1, 0, 0, 0);
      s0 = __builtin_amdgcn_mfma_f32_32x32x16_bf16(aR[2], b0[2], s0, 0, 0, 0);
      s1 = __builtin_amdgcn_mfma_f32_32x32x16_bf16(aR[3], b0[3], s1, 0, 0, 0);
      if (jj < 7) {
        const size_t Gj = Gj0 + jj * 2 + 2;
#pragma unroll
        for (int kk = 0; kk < 4; ++kk)
          b0[kk] = *(const bf16x8*)(DHf + Gj * 2048 + kk * 512 + lane * 8);
      }
#pragma unroll
      for (int r = 0; r < 16; ++r)
        racc[r] += __builtin_amdgcn_exp2f(
            __builtin_fmaf(s0[r] + s1[r], LOG2E, lbv));
    }
    {
      const float lbv = lbe[jbase + (jj * 2 + 1) * 32 + l31];
      f32x16 s0 = zero16(), s1 = zero16();
      s0 = __builtin_amdgcn_mfma_f32_32x32x16_bf16(aR[0], b1[0], s0, 0, 0, 0);
      s1 = __builtin_amdgcn_mfma_f32_32x32x16_bf16(aR[1], b1[1], s1, 0, 0, 0);
      s0 = __builtin_amdgcn_mfma_f32_32x32x16_bf16(aR[2], b1[2], s0, 0, 0, 0);
      s1 = __builtin_amdgcn_mfma_f32_32x32x16_bf16(aR[3], b1[3], s1, 0, 0, 0);
      if (jj < 7) {
        const size_t Gj = Gj0 + jj * 2 + 3;
#pragma unroll
        for (int kk = 0; kk < 4; ++kk)
          b1[kk] = *(const bf16x8*)(DHf + Gj * 2048 + kk * 512 + lane * 8);
      }
#pragma unroll
      for (int r = 0; r < 16; ++r)
        racc[r] += __builtin_amdgcn_exp2f(
            __builtin_fmaf(s0[r] + s1[r], LOG2E, lbv));
    }
  }
#pragma unroll
  for (int r = 0; r < 16; ++r) {
    int tl = wave * 32 + (r & 3) + 8 * (r >> 2) + 4 * h;
    red2[tl][l31] = racc[r];
  }
  __syncthreads();
  if (tid < 256) {
    float s = 0.f;
#pragma unroll 8
    for (int c = 0; c < 32; ++c) s += red2[tid][c];
    atomicAdd(&rowsum[t0 + tid], s);
  }
}

// ---------------------------------------------------------------------------
// K2b: Hbf_sw = bf16(H*rinv[t]) pre-swizzled to k_z's LDS image.
//      grid 256 x 256.  (R4-proven)
// ---------------------------------------------------------------------------
__global__ __launch_bounds__(256) void k_scaleH(const float* __restrict__ H,
                                                const float* __restrict__ rowsum,
                                                __bf16* __restrict__ Hbf_sw) {
  __shared__ float rinvL[64];
  const int tid = threadIdx.x;
  const int bx = blockIdx.x;
  const int tblk = bx >> 1, dh = bx & 1;
  const int t0 = tblk * 64;
  if (tid < 64) rinvL[tid] = 1.0f / rowsum[t0 + tid];
  __syncthreads();
#pragma unroll
  for (int itr = 0; itr < 4; ++itr) {
    int idx = itr * 256 + tid;
    int dl = idx >> 3, tbp = idx & 7;
    int d = dh * 128 + dl;
    int swz = (d ^ (d >> 3)) & 7;
    int tloc = (tbp ^ swz) << 3;
    const float4* hp = (const float4*)(H + (size_t)d * T_DIM + t0 + tloc);
    float4 v0 = hp[0], v1 = hp[1];
    float4 r0 = *(const float4*)&rinvL[tloc];
    float4 r1 = *(const float4*)&rinvL[tloc + 4];
    bf16x8 w;
    w[0] = (__bf16)(v0.x * r0.x); w[1] = (__bf16)(v0.y * r0.y);
    w[2] = (__bf16)(v0.z * r0.z); w[3] = (__bf16)(v0.w * r0.w);
    w[4] = (__bf16)(v1.x * r1.x); w[5] = (__bf16)(v1.y * r1.y);
    w[6] = (__bf16)(v1.z * r1.z); w[7] = (__bf16)(v1.w * r1.w);
    *(bf16x8*)(Hbf_sw + (size_t)tblk * 16384 + (size_t)d * 64 + tbp * 8) = w;
  }
}

// ---------------------------------------------------------------------------
// K3 v3: Zp[ts][d][j] = sum_{t} H'[d][t]*E[t][j].  R11 structure (512 thr,
//     16 waves/CU, DMA staging) with ONE scheduling change: the exp tail is
//     moved AFTER Z_PHASE.  Per iter: S-MFMAs -> Z-MFMAs (hide S-MFMA
//     latency) -> exp+Pt-write (VALU/trans overlaps other waves' Z-MFMAs)
//     -> barrier.  No sync/buffer changes: Pt[p^1] writes still precede the
//     same barrier; Z still reads buffer p.  sv (16 f32) lives across Z.
// ---------------------------------------------------------------------------
__global__ __launch_bounds__(512, 4) void k_z(const __bf16* __restrict__ Hbf_sw,
                                              const __bf16* __restrict__ DHf,
                                              const float* __restrict__ lbe,
                                              float* __restrict__ Zp) {
  __shared__ __bf16 Hs[2][128 * 64];  // [dl][t] swizzled, 2 x 16 KB
  __shared__ __bf16 Pt[2][128 * 64];  // [j][t] swizzled,  2 x 16 KB
  const int tid = threadIdx.x;
  const int lane = tid & 63;
  const int wave = tid >> 6;  // 0..7
  const int h = lane >> 5;
  const int l31 = lane & 31;
  const int bx = blockIdx.x;
  const int ts = bx & 3;
  const int dh = (bx >> 2) & 1;
  const int j0 = (bx >> 3) * 128;
  const int s_tt = wave & 1, s_jg = wave >> 1;  // S roles: t-half, j32-group
  const int dq = wave & 1, jv = wave >> 1;      // Z roles: d64-half, j32-group
  bf16x8 bS[4];
  float lbv;
  {
    const size_t Gj = (size_t)(j0 >> 5) + s_jg;
#pragma unroll
    for (int kk = 0; kk < 4; ++kk)
      bS[kk] = *(const bf16x8*)(DHf + Gj * 2048 + kk * 512 + lane * 8);
    lbv = lbe[j0 + s_jg * 32 + l31];
  }
  f32x16 acc[2];
#pragma unroll
  for (int u = 0; u < 2; ++u) acc[u] = zero16();
  f32x16 sv;  // S-MFMA result, lives across Z_PHASE

#define DMA_HS(buf_, it_)                                                       \
  {                                                                             \
    const __bf16* gsrc =                                                        \
        Hbf_sw + (size_t)(ts * 32 + (it_)) * 16384 + (size_t)dh * 8192;         \
    _Pragma("unroll") for (int r = 0; r < 2; ++r) {                             \
      int chunk = wave * 2 + r;                                                 \
      __builtin_amdgcn_global_load_lds(                                         \
          (const __attribute__((address_space(1))) unsigned int*)(gsrc +        \
              chunk * 512 + lane * 8),                                          \
          (__attribute__((address_space(3))) unsigned int*)(&Hs[buf_][0] +      \
              chunk * 512),                                                     \
          16, 0, 0);                                                            \
    }                                                                           \
  }

#define LOAD_AR(reg_, n_)                                                       \
  {                                                                             \
    const size_t Gt_ = (size_t)(ts * 64 + (n_)*2 + s_tt);                       \
    _Pragma("unroll") for (int kk = 0; kk < 4; ++kk)                            \
        (reg_)[kk] = *(const bf16x8*)(DHf + Gt_ * 2048 + kk * 512 + lane * 8);  \
  }

  // S matrix-multiply only: sv = (DH_t-tile)^T x (DH_j-group)
#define S_MM(reg_)                                                              \
  {                                                                             \
    sv = zero16();                                                              \
    sv = __builtin_amdgcn_mfma_f32_32x32x16_bf16((reg_)[0], bS[0], sv, 0, 0, 0);\
    sv = __builtin_amdgcn_mfma_f32_32x32x16_bf16((reg_)[1], bS[1], sv, 0, 0, 0);\
    sv = __builtin_amdgcn_mfma_f32_32x32x16_bf16((reg_)[2], bS[2], sv, 0, 0, 0);\
    sv = __builtin_amdgcn_mfma_f32_32x32x16_bf16((reg_)[3], bS[3], sv, 0, 0, 0);\
  }

  // exp tail + Pt write (consumes sv)
#define S_EXP(p_)                                                               \
  {                                                                             \
    const int jl = s_jg * 32 + l31;                                             \
    const int sj = (jl ^ (jl >> 3)) & 7;                                        \
    _Pragma("unroll") for (int g = 0; g < 4; ++g) {                             \
      const int tl = s_tt * 32 + g * 8 + 4 * h;                                 \
      bf16x4 pv;                                                                \
      pv[0] = (__bf16)__builtin_amdgcn_exp2f(                                   \
          __builtin_fmaf(sv[g * 4 + 0], LOG2E, lbv));                           \
      pv[1] = (__bf16)__builtin_amdgcn_exp2f(                                   \
          __builtin_fmaf(sv[g * 4 + 1], LOG2E, lbv));                           \
      pv[2] = (__bf16)__builtin_amdgcn_exp2f(                                   \
          __builtin_fmaf(sv[g * 4 + 2], LOG2E, lbv));                           \
      pv[3] = (__bf16)__builtin_amdgcn_exp2f(                                   \
          __builtin_fmaf(sv[g * 4 + 3], LOG2E, lbv));                           \
      const int cchunk = tl >> 3;                                               \
      *(bf16x4*)&Pt[p_][jl * 64 + ((cchunk ^ sj) << 3) + 4 * h] = pv;           \
    }                                                                           \
  }

#define Z_PHASE(p_)                                                             \
  {                                                                             \
    __builtin_amdgcn_s_setprio(1);                                              \
    _Pragma("unroll") for (int kk = 0; kk < 4; ++kk) {                          \
      const int c = kk * 2 + h;                                                 \
      bf16x8 af[2], bw;                                                         \
      _Pragma("unroll") for (int u = 0; u < 2; ++u) {                           \
        int dl = dq * 64 + u * 32 + l31;                                        \
        af[u] =                                                                 \
            *(const bf16x8*)&Hs[p_][dl * 64 + ((c ^ ((dl ^ (dl >> 3)) & 7)) << 3)]; \
      }                                                                         \
      {                                                                         \
        int j = jv * 32 + l31;                                                  \
        bw = *(const bf16x8*)&Pt[p_][j * 64 + ((c ^ ((j ^ (j >> 3)) & 7)) << 3)]; \
      }                                                                         \
      _Pragma("unroll") for (int u = 0; u < 2; ++u)                             \
          acc[u] = __builtin_amdgcn_mfma_f32_32x32x16_bf16(af[u], bw, acc[u],   \
                                                           0, 0, 0);            \
    }                                                                           \
    __builtin_amdgcn_s_setprio(0);                                              \
  }

  bf16x8 aR[4], aRn[4];
  LOAD_AR(aR, 0);
  DMA_HS(0, 0);
  S_MM(aR);
  S_EXP(0);           // Pt[0] for tile 0
  LOAD_AR(aRn, 1);    // frags for tile 1
  __syncthreads();    // Hs[0] drained, Pt[0] visible

  for (int ii = 0; ii < 16; ++ii) {
    const int it0 = ii * 2;
    // ---- even iter: consume buffers 0; build [1] ----
    DMA_HS(1, it0 + 1);
    if (it0 < 30) LOAD_AR(aR, it0 + 2);
    S_MM(aRn);        // S-MFMAs for Pt[1] (tile it0+1)
    Z_PHASE(0);       // 8 MFMAs hide S-MFMA latency
    S_EXP(1);         // exp tail overlaps other waves' Z-MFMAs
    __syncthreads();
    // ---- odd iter: consume buffers 1; build [0] ----
    if (it0 + 1 < 31) {
      DMA_HS(0, it0 + 2);
      S_MM(aR);       // S-MFMAs for Pt[0] (tile it0+2)
    }
    if (it0 + 1 < 30) LOAD_AR(aRn, it0 + 3);
    Z_PHASE(1);
    if (it0 + 1 < 31) S_EXP(0);
    __syncthreads();
  }
#undef Z_PHASE
#undef S_EXP
#undef S_MM
#undef LOAD_AR
#undef DMA_HS
  // ---- epilogue: coalesced plane stores ----
  float* zp = Zp + (size_t)ts * (256 * (size_t)T_DIM);
#pragma unroll
  for (int u = 0; u < 2; ++u)
#pragma unroll
    for (int r = 0; r < 16; ++r) {
      int d = dh * 128 + dq * 64 + u * 32 + (r & 3) + 8 * (r >> 2) + 4 * h;
      int j = j0 + jv * 32 + l31;
      zp[(size_t)d * T_DIM + j] = acc[u][r];
    }
}

// ---------------------------------------------------------------------------
// K4: Z = l2 * sum_{ts=0..3} Zp[ts]. grid 2048 x 256. (unchanged)
// ---------------------------------------------------------------------------
__global__ __launch_bounds__(256) void k_zred(const float* __restrict__ Zp,
                                              const float* __restrict__ l2p,
                                              float* __restrict__ Z) {
  const int i = blockIdx.x * 256 + threadIdx.x;
  const float l2v = l2p[0];
  const float4* zp4 = (const float4*)Zp;
  float4 a = zp4[i];
#pragma unroll
  for (int s = 1; s < 4; ++s) {
    float4 b = zp4[(size_t)s * 524288 + i];
    a.x += b.x; a.y += b.y; a.z += b.z; a.w += b.w;
  }
  float4 o = {a.x * l2v, a.y * l2v, a.z * l2v, a.w * l2v};
  ((float4*)Z)[i] = o;
}

// ---------------------------------------------------------------------------
extern "C" void kernel_launch(void* const* d_in, const int* in_sizes, int n_in,
                              void* d_out, int out_size, void* d_ws,
                              size_t ws_size, hipStream_t stream) {
  (void)in_sizes; (void)n_in; (void)out_size; (void)ws_size;
  const float* H = (const float*)d_in[0];
  const float* Dm = (const float*)d_in[1];
  const float* l2 = (const float*)d_in[2];
  float* Z = (float*)d_out;
  char* ws = (char*)d_ws;
  __bf16* DHf = (__bf16*)ws;                        // 1,048,576 B
  float* lbe = (float*)(ws + 1048576);              // 32,768 B
  float* rowsum = (float*)(ws + 1048576 + 32768);   // 32,768 B
  __bf16* Hbf_sw = (__bf16*)(ws + 1114112);         // 4,194,304 B
  float* Zp = (float*)(ws + 5308416);               // 33,554,432 B (4 planes)

  k_dh<<<256, 256, 0, stream>>>(H, Dm, DHf, lbe, rowsum);
  k_rowsum<<<512, 512, 0, stream>>>(DHf, lbe, rowsum);
  k_scaleH<<<256, 256, 0, stream>>>(H, rowsum, Hbf_sw);
  k_z<<<512, 512, 0, stream>>>(Hbf_sw, DHf, lbe, Zp);
  k_zred<<<2048, 256, 0, stream>>>(Zp, l2, Z);
}

// Round 15
// 143.308 us; speedup vs baseline: 1.0114x; 1.0114x over previous
//
#include <hip/hip_runtime.h>

#define T_DIM 8192
#define D_DIM 256
#define N_DIM 64
#define LOG2E 1.44269504f

typedef __bf16 bf16x8 __attribute__((ext_vector_type(8)));
typedef __bf16 bf16x4 __attribute__((ext_vector_type(4)));
typedef float f32x16 __attribute__((ext_vector_type(16)));

__device__ __forceinline__ f32x16 zero16() {
  f32x16 v;
#pragma unroll
  for (int i = 0; i < 16; ++i) v[i] = 0.f;
  return v;
}

// DHf: fragment-major. Row-group G=t>>5, chunk c=kk*2+h, lane l31:
// DHf[G*2048 + c*256 + l31*8 .. +7] = DH[n=c*8+e][t=G*32+l31].

// ---------------------------------------------------------------------------
// K1 v2: DHf + lbe + rowsum=0. t32 blocks, grid 256 x 256 — full machine,
//     4 waves = nh(2 n-tiles) x kh(2 K-halves), K-split partials reduced in
//     LDS. 47KB LDS -> 3 blk/CU.  (R12-proven)
// ---------------------------------------------------------------------------
__global__ __launch_bounds__(256) void k_dh(const float* __restrict__ H,
                                            const float* __restrict__ Dm,
                                            __bf16* __restrict__ DHf,
                                            float* __restrict__ lbe,
                                            float* __restrict__ rowsum) {
  __shared__ __bf16 HlThi[32 * 264];
  __shared__ __bf16 HlTlo[32 * 264];
  __shared__ __bf16 DHs[32 * 72];
  __shared__ float redf[2][32][33];
  const int tid = threadIdx.x;
  const int t0 = blockIdx.x * 32;
  const int lane = tid & 63;
  const int wave = tid >> 6;  // 0..3
  const int h = lane >> 5;
  const int l31 = lane & 31;
  const float4* H4 = (const float4*)H;
#pragma unroll
  for (int r = 0; r < 8; ++r) {
    int idx = r * 256 + tid;
    int d = idx >> 3, tc = idx & 7;
    float4 v = H4[(size_t)d * (T_DIM / 4) + (t0 >> 2) + tc];
    float vv[4] = {v.x, v.y, v.z, v.w};
#pragma unroll
    for (int i = 0; i < 4; ++i) {
      __bf16 hi = (__bf16)vv[i];
      float lo = vv[i] - (float)hi;
      HlThi[(tc * 4 + i) * 264 + d] = hi;
      HlTlo[(tc * 4 + i) * 264 + d] = (__bf16)lo;
    }
  }
  __syncthreads();
  const int nh = wave & 1;   // n-tile
  const int kh = wave >> 1;  // K-half
  const int m = l31;
  const int n = nh * 32 + l31;
  f32x16 c = zero16();
#pragma unroll
  for (int kq = 0; kq < 8; ++kq) {
    const int kk = kh * 8 + kq;
    bf16x8 ahi = *(const bf16x8*)&HlThi[m * 264 + kk * 16 + h * 8];
    bf16x8 alo = *(const bf16x8*)&HlTlo[m * 264 + kk * 16 + h * 8];
    const float4* dp = (const float4*)(Dm + (size_t)n * 256 + kk * 16 + h * 8);
    float4 b0 = dp[0], b1 = dp[1];
    float bv[8] = {b0.x, b0.y, b0.z, b0.w, b1.x, b1.y, b1.z, b1.w};
    bf16x8 bhi, blo;
#pragma unroll
    for (int i = 0; i < 8; ++i) {
      __bf16 hi = (__bf16)bv[i];
      bhi[i] = hi;
      blo[i] = (__bf16)(bv[i] - (float)hi);
    }
    c = __builtin_amdgcn_mfma_f32_32x32x16_bf16(ahi, bhi, c, 0, 0, 0);
    c = __builtin_amdgcn_mfma_f32_32x32x16_bf16(ahi, blo, c, 0, 0, 0);
    c = __builtin_amdgcn_mfma_f32_32x32x16_bf16(alo, bhi, c, 0, 0, 0);
  }
  if (kh == 1) {
#pragma unroll
    for (int r = 0; r < 16; ++r) {
      int row = (r & 3) + 8 * (r >> 2) + 4 * h;
      redf[nh][row][l31] = c[r];
    }
  }
  __syncthreads();
  if (kh == 0) {
#pragma unroll
    for (int r = 0; r < 16; ++r) {
      int row = (r & 3) + 8 * (r >> 2) + 4 * h;
      DHs[row * 72 + n] = (__bf16)(c[r] + redf[nh][row][l31]);
    }
  }
  __syncthreads();
  {  // export: 256 threads cover cc(8) x l(32)
    int cc = tid >> 5, l = tid & 31;
    bf16x8 w = *(const bf16x8*)&DHs[l * 72 + cc * 8];
    *(bf16x8*)(DHf + (size_t)blockIdx.x * 2048 + cc * 256 + l * 8) = w;
  }
  if (tid < 32) {
    float s = 0.f;
#pragma unroll
    for (int q = 0; q < 8; ++q) {
      bf16x8 w = *(const bf16x8*)&DHs[tid * 72 + q * 8];
#pragma unroll
      for (int i = 0; i < 8; ++i) { float f = (float)w[i]; s += f * f; }
    }
    lbe[t0 + tid] = -0.5f * s * LOG2E;
    rowsum[t0 + tid] = 0.f;
  }
}

// ---------------------------------------------------------------------------
// K2 v4: rowsum[t] += sum_j exp(S+lb). grid 512 x 512.  (R10-proven)
// ---------------------------------------------------------------------------
__global__ __launch_bounds__(512, 4) void k_rowsum(const __bf16* __restrict__ DHf,
                                                   const float* __restrict__ lbe,
                                                   float* __restrict__ rowsum) {
  __shared__ float red2[256][33];
  const int tid = threadIdx.x;
  const int lane = tid & 63;
  const int wave = tid >> 6;
  const int h = lane >> 5;
  const int l31 = lane & 31;
  const int t0 = (int)(blockIdx.x >> 4) * 256;
  const int jbase = (int)(blockIdx.x & 15) * 512;
  const size_t Gt = (size_t)(t0 >> 5) + wave;
  const size_t Gj0 = (size_t)(jbase >> 5);
  bf16x8 aR[4];
#pragma unroll
  for (int kk = 0; kk < 4; ++kk)
    aR[kk] = *(const bf16x8*)(DHf + Gt * 2048 + kk * 512 + lane * 8);
  float racc[16];
#pragma unroll
  for (int r = 0; r < 16; ++r) racc[r] = 0.f;
  bf16x8 b0[4], b1[4];
#pragma unroll
  for (int kk = 0; kk < 4; ++kk) {
    b0[kk] = *(const bf16x8*)(DHf + Gj0 * 2048 + kk * 512 + lane * 8);
    b1[kk] = *(const bf16x8*)(DHf + (Gj0 + 1) * 2048 + kk * 512 + lane * 8);
  }
#pragma unroll
  for (int jj = 0; jj < 8; ++jj) {
    {
      const float lbv = lbe[jbase + (jj * 2) * 32 + l31];
      f32x16 s0 = zero16(), s1 = zero16();
      s0 = __builtin_amdgcn_mfma_f32_32x32x16_bf16(aR[0], b0[0], s0, 0, 0, 0);
      s1 = __builtin_amdgcn_mfma_f32_32x32x16_bf16(aR[1], b0[1], s1, 0, 0, 0);
      s0 = __builtin_amdgcn_mfma_f32_32x32x16_bf16(aR[2], b0[2], s0, 0, 0, 0);
      s1 = __builtin_amdgcn_mfma_f32_32x32x16_bf16(aR[3], b0[3], s1, 0, 0, 0);
      if (jj < 7) {
        const size_t Gj = Gj0 + jj * 2 + 2;
#pragma unroll
        for (int kk = 0; kk < 4; ++kk)
          b0[kk] = *(const bf16x8*)(DHf + Gj * 2048 + kk * 512 + lane * 8);
      }
#pragma unroll
      for (int r = 0; r < 16; ++r)
        racc[r] += __builtin_amdgcn_exp2f(
            __builtin_fmaf(s0[r] + s1[r], LOG2E, lbv));
    }
    {
      const float lbv = lbe[jbase + (jj * 2 + 1) * 32 + l31];
      f32x16 s0 = zero16(), s1 = zero16();
      s0 = __builtin_amdgcn_mfma_f32_32x32x16_bf16(aR[0], b1[0], s0, 0, 0, 0);
      s1 = __builtin_amdgcn_mfma_f32_32x32x16_bf16(aR[1], b1[1], s1, 0, 0, 0);
      s0 = __builtin_amdgcn_mfma_f32_32x32x16_bf16(aR[2], b1[2], s0, 0, 0, 0);
      s1 = __builtin_amdgcn_mfma_f32_32x32x16_bf16(aR[3], b1[3], s1, 0, 0, 0);
      if (jj < 7) {
        const size_t Gj = Gj0 + jj * 2 + 3;
#pragma unroll
        for (int kk = 0; kk < 4; ++kk)
          b1[kk] = *(const bf16x8*)(DHf + Gj * 2048 + kk * 512 + lane * 8);
      }
#pragma unroll
      for (int r = 0; r < 16; ++r)
        racc[r] += __builtin_amdgcn_exp2f(
            __builtin_fmaf(s0[r] + s1[r], LOG2E, lbv));
    }
  }
#pragma unroll
  for (int r = 0; r < 16; ++r) {
    int tl = wave * 32 + (r & 3) + 8 * (r >> 2) + 4 * h;
    red2[tl][l31] = racc[r];
  }
  __syncthreads();
  if (tid < 256) {
    float s = 0.f;
#pragma unroll 8
    for (int c = 0; c < 32; ++c) s += red2[tid][c];
    atomicAdd(&rowsum[t0 + tid], s);
  }
}

// ---------------------------------------------------------------------------
// K2b: Hbf_sw = bf16(H*rinv[t]) pre-swizzled to k_z's LDS image.
//      grid 256 x 256.  (R4-proven)
// ---------------------------------------------------------------------------
__global__ __launch_bounds__(256) void k_scaleH(const float* __restrict__ H,
                                                const float* __restrict__ rowsum,
                                                __bf16* __restrict__ Hbf_sw) {
  __shared__ float rinvL[64];
  const int tid = threadIdx.x;
  const int bx = blockIdx.x;
  const int tblk = bx >> 1, dh = bx & 1;
  const int t0 = tblk * 64;
  if (tid < 64) rinvL[tid] = 1.0f / rowsum[t0 + tid];
  __syncthreads();
#pragma unroll
  for (int itr = 0; itr < 4; ++itr) {
    int idx = itr * 256 + tid;
    int dl = idx >> 3, tbp = idx & 7;
    int d = dh * 128 + dl;
    int swz = (d ^ (d >> 3)) & 7;
    int tloc = (tbp ^ swz) << 3;
    const float4* hp = (const float4*)(H + (size_t)d * T_DIM + t0 + tloc);
    float4 v0 = hp[0], v1 = hp[1];
    float4 r0 = *(const float4*)&rinvL[tloc];
    float4 r1 = *(const float4*)&rinvL[tloc + 4];
    bf16x8 w;
    w[0] = (__bf16)(v0.x * r0.x); w[1] = (__bf16)(v0.y * r0.y);
    w[2] = (__bf16)(v0.z * r0.z); w[3] = (__bf16)(v0.w * r0.w);
    w[4] = (__bf16)(v1.x * r1.x); w[5] = (__bf16)(v1.y * r1.y);
    w[6] = (__bf16)(v1.z * r1.z); w[7] = (__bf16)(v1.w * r1.w);
    *(bf16x8*)(Hbf_sw + (size_t)tblk * 16384 + (size_t)d * 64 + tbp * 8) = w;
  }
}

// ---------------------------------------------------------------------------
// K3 v2: Zp[ts][d][j] = sum_{t} H'[d][t]*E[t][j].  (R13-proven best, 60.4us:
//     512 thr / 8 waves / 16 waves/CU, global_load_lds DMA staging, dbuf
//     Hs/Pt, aR/aRn dbuf, setprio, plane stores.  R14's exp-tail reorder
//     REVERTED: keeping sv live across Z_PHASE raised reg pressure ->
//     AGPR shuffling + FETCH 6.3->10.4MB, MfmaUtil -3, +2.5us.)
// ---------------------------------------------------------------------------
__global__ __launch_bounds__(512, 4) void k_z(const __bf16* __restrict__ Hbf_sw,
                                              const __bf16* __restrict__ DHf,
                                              const float* __restrict__ lbe,
                                              float* __restrict__ Zp) {
  __shared__ __bf16 Hs[2][128 * 64];  // [dl][t] swizzled, 2 x 16 KB
  __shared__ __bf16 Pt[2][128 * 64];  // [j][t] swizzled,  2 x 16 KB
  const int tid = threadIdx.x;
  const int lane = tid & 63;
  const int wave = tid >> 6;  // 0..7
  const int h = lane >> 5;
  const int l31 = lane & 31;
  const int bx = blockIdx.x;
  const int ts = bx & 3;
  const int dh = (bx >> 2) & 1;
  const int j0 = (bx >> 3) * 128;
  const int s_tt = wave & 1, s_jg = wave >> 1;  // S roles: t-half, j32-group
  const int dq = wave & 1, jv = wave >> 1;      // Z roles: d64-half, j32-group
  bf16x8 bS[4];
  float lbv;
  {
    const size_t Gj = (size_t)(j0 >> 5) + s_jg;
#pragma unroll
    for (int kk = 0; kk < 4; ++kk)
      bS[kk] = *(const bf16x8*)(DHf + Gj * 2048 + kk * 512 + lane * 8);
    lbv = lbe[j0 + s_jg * 32 + l31];
  }
  f32x16 acc[2];
#pragma unroll
  for (int u = 0; u < 2; ++u) acc[u] = zero16();

#define DMA_HS(buf_, it_)                                                       \
  {                                                                             \
    const __bf16* gsrc =                                                        \
        Hbf_sw + (size_t)(ts * 32 + (it_)) * 16384 + (size_t)dh * 8192;         \
    _Pragma("unroll") for (int r = 0; r < 2; ++r) {                             \
      int chunk = wave * 2 + r;                                                 \
      __builtin_amdgcn_global_load_lds(                                         \
          (const __attribute__((address_space(1))) unsigned int*)(gsrc +        \
              chunk * 512 + lane * 8),                                          \
          (__attribute__((address_space(3))) unsigned int*)(&Hs[buf_][0] +      \
              chunk * 512),                                                     \
          16, 0, 0);                                                            \
    }                                                                           \
  }

#define LOAD_AR(reg_, n_)                                                       \
  {                                                                             \
    const size_t Gt_ = (size_t)(ts * 64 + (n_)*2 + s_tt);                       \
    _Pragma("unroll") for (int kk = 0; kk < 4; ++kk)                            \
        (reg_)[kk] = *(const bf16x8*)(DHf + Gt_ * 2048 + kk * 512 + lane * 8);  \
  }

#define S_PHASE(p_, reg_)                                                       \
  {                                                                             \
    f32x16 s = zero16();                                                        \
    s = __builtin_amdgcn_mfma_f32_32x32x16_bf16((reg_)[0], bS[0], s, 0, 0, 0);  \
    s = __builtin_amdgcn_mfma_f32_32x32x16_bf16((reg_)[1], bS[1], s, 0, 0, 0);  \
    s = __builtin_amdgcn_mfma_f32_32x32x16_bf16((reg_)[2], bS[2], s, 0, 0, 0);  \
    s = __builtin_amdgcn_mfma_f32_32x32x16_bf16((reg_)[3], bS[3], s, 0, 0, 0);  \
    const int jl = s_jg * 32 + l31;                                             \
    const int sj = (jl ^ (jl >> 3)) & 7;                                        \
    _Pragma("unroll") for (int g = 0; g < 4; ++g) {                             \
      const int tl = s_tt * 32 + g * 8 + 4 * h;                                 \
      bf16x4 pv;                                                                \
      pv[0] = (__bf16)__builtin_amdgcn_exp2f(                                   \
          __builtin_fmaf(s[g * 4 + 0], LOG2E, lbv));                            \
      pv[1] = (__bf16)__builtin_amdgcn_exp2f(                                   \
          __builtin_fmaf(s[g * 4 + 1], LOG2E, lbv));                            \
      pv[2] = (__bf16)__builtin_amdgcn_exp2f(                                   \
          __builtin_fmaf(s[g * 4 + 2], LOG2E, lbv));                            \
      pv[3] = (__bf16)__builtin_amdgcn_exp2f(                                   \
          __builtin_fmaf(s[g * 4 + 3], LOG2E, lbv));                            \
      const int cchunk = tl >> 3;                                               \
      *(bf16x4*)&Pt[p_][jl * 64 + ((cchunk ^ sj) << 3) + 4 * h] = pv;           \
    }                                                                           \
  }

#define Z_PHASE(p_)                                                             \
  {                                                                             \
    __builtin_amdgcn_s_setprio(1);                                              \
    _Pragma("unroll") for (int kk = 0; kk < 4; ++kk) {                          \
      const int c = kk * 2 + h;                                                 \
      bf16x8 af[2], bw;                                                         \
      _Pragma("unroll") for (int u = 0; u < 2; ++u) {                           \
        int dl = dq * 64 + u * 32 + l31;                                        \
        af[u] =                                                                 \
            *(const bf16x8*)&Hs[p_][dl * 64 + ((c ^ ((dl ^ (dl >> 3)) & 7)) << 3)]; \
      }                                                                         \
      {                                                                         \
        int j = jv * 32 + l31;                                                  \
        bw = *(const bf16x8*)&Pt[p_][j * 64 + ((c ^ ((j ^ (j >> 3)) & 7)) << 3)]; \
      }                                                                         \
      _Pragma("unroll") for (int u = 0; u < 2; ++u)                             \
          acc[u] = __builtin_amdgcn_mfma_f32_32x32x16_bf16(af[u], bw, acc[u],   \
                                                           0, 0, 0);            \
    }                                                                           \
    __builtin_amdgcn_s_setprio(0);                                              \
  }

  bf16x8 aR[4], aRn[4];
  LOAD_AR(aR, 0);
  DMA_HS(0, 0);
  S_PHASE(0, aR);
  LOAD_AR(aRn, 1);
  __syncthreads();

  for (int ii = 0; ii < 16; ++ii) {
    const int it0 = ii * 2;
    DMA_HS(1, it0 + 1);
    if (it0 < 30) LOAD_AR(aR, it0 + 2);
    S_PHASE(1, aRn);
    Z_PHASE(0);
    __syncthreads();
    if (it0 + 1 < 31) {
      DMA_HS(0, it0 + 2);
      S_PHASE(0, aR);
    }
    if (it0 + 1 < 30) LOAD_AR(aRn, it0 + 3);
    Z_PHASE(1);
    __syncthreads();
  }
#undef Z_PHASE
#undef S_PHASE
#undef LOAD_AR
#undef DMA_HS
  // ---- epilogue: coalesced plane stores ----
  float* zp = Zp + (size_t)ts * (256 * (size_t)T_DIM);
#pragma unroll
  for (int u = 0; u < 2; ++u)
#pragma unroll
    for (int r = 0; r < 16; ++r) {
      int d = dh * 128 + dq * 64 + u * 32 + (r & 3) + 8 * (r >> 2) + 4 * h;
      int j = j0 + jv * 32 + l31;
      zp[(size_t)d * T_DIM + j] = acc[u][r];
    }
}

// ---------------------------------------------------------------------------
// K4: Z = l2 * sum_{ts=0..3} Zp[ts]. grid 2048 x 256. (unchanged)
// ---------------------------------------------------------------------------
__global__ __launch_bounds__(256) void k_zred(const float* __restrict__ Zp,
                                              const float* __restrict__ l2p,
                                              float* __restrict__ Z) {
  const int i = blockIdx.x * 256 + threadIdx.x;
  const float l2v = l2p[0];
  const float4* zp4 = (const float4*)Zp;
  float4 a = zp4[i];
#pragma unroll
  for (int s = 1; s < 4; ++s) {
    float4 b = zp4[(size_t)s * 524288 + i];
    a.x += b.x; a.y += b.y; a.z += b.z; a.w += b.w;
  }
  float4 o = {a.x * l2v, a.y * l2v, a.z * l2v, a.w * l2v};
  ((float4*)Z)[i] = o;
}

// ---------------------------------------------------------------------------
extern "C" void kernel_launch(void* const* d_in, const int* in_sizes, int n_in,
                              void* d_out, int out_size, void* d_ws,
                              size_t ws_size, hipStream_t stream) {
  (void)in_sizes; (void)n_in; (void)out_size; (void)ws_size;
  const float* H = (const float*)d_in[0];
  const float* Dm = (const float*)d_in[1];
  const float* l2 = (const float*)d_in[2];
  float* Z = (float*)d_out;
  char* ws = (char*)d_ws;
  __bf16* DHf = (__bf16*)ws;                        // 1,048,576 B
  float* lbe = (float*)(ws + 1048576);              // 32,768 B
  float* rowsum = (float*)(ws + 1048576 + 32768);   // 32,768 B
  __bf16* Hbf_sw = (__bf16*)(ws + 1114112);         // 4,194,304 B
  float* Zp = (float*)(ws + 5308416);               // 33,554,432 B (4 planes)

  k_dh<<<256, 256, 0, stream>>>(H, Dm, DHf, lbe, rowsum);
  k_rowsum<<<512, 512, 0, stream>>>(DHf, lbe, rowsum);
  k_scaleH<<<256, 256, 0, stream>>>(H, rowsum, Hbf_sw);
  k_z<<<512, 512, 0, stream>>>(Hbf_sw, DHf, lbe, Zp);
  k_zred<<<2048, 256, 0, stream>>>(Zp, l2, Z);
}